// Round 1
// baseline (361.044 us; speedup 1.0000x reference)
//
#include <hip/hip_runtime.h>
#include <hip/hip_bf16.h>

// out[b,k,oc,x] = sum_i W[k,oc,i] * in[b,i,k,x] + bias[k,oc]
// B=4096, Cin=Cout=128, K(offsets)=9, X=9.
// Memory-bound: 340 MB min traffic ~54us @6.3TB/s. bf16 MFMA compute ~4.6us.
// R1: XCD-aware swizzle (k-siblings of a btile share one XCD's L2); W direct from global.
// R2: latency fix — staging was 36 serialized scalar-load->ds_write chains (VGPR=40,
//     ~1 outstanding load/wave, all pipes <21% busy). Now: affine row-per-thread
//     decomposition (zero divisions), 12 hoisted 16B loads/thread issued before any
//     use, one-base-reg + 36 imm-offset ds_write_b16 (2-way bank alias = free),
//     launch_bounds(512,4) so the batch lives in registers.

#define NB   4096
#define CINC 128
#define COUTC 128
#define NK   9
#define NX   9
#define BT   16               // b's per workgroup
#define NCOL (BT * NX)        // 144 columns per workgroup
#define LDK  136              // padded row length (shorts): 16B-aligned rows

typedef __attribute__((ext_vector_type(8))) short short8;
typedef __attribute__((ext_vector_type(4))) float floatx4;

// 16B payload with 4B alignment: rows start at float granularity (addr = 324B*i + 36B*k
// offsets), so float4 (align 16) is illegal; gfx9+ global_load_dwordx4 only needs
// dword alignment, and clang emits it for this aggregate.
struct F4 { float x, y, z, w; };

__device__ __forceinline__ short f2bf(float f) {
    union { float f; unsigned u; } v; v.f = f;
    unsigned r = v.u + 0x7fff + ((v.u >> 16) & 1);  // RNE; inputs are finite normals
    return (short)(r >> 16);
}

__global__ __launch_bounds__(512, 4) void GatherVertical_40656160424516_kernel(
    const float* __restrict__ in, const float* __restrict__ w,
    const float* __restrict__ bias, float* __restrict__ out)
{
    __shared__ short Il[NCOL * LDK];    // [col=(bl,x)][i] bf16, 39168 B

    const int t = threadIdx.x;

    // ---- XCD swizzle: siblings (same btile, k=0..8) land on the same XCD,
    // adjacent in that XCD's dispatch stream.
    const int j = blockIdx.x;
    const int xcd = j & 7;
    const int slot = j >> 3;          // 0..287 per XCD
    const int grp = slot / 9;         // 0..31
    const int k = slot - grp * 9;     // 0..8
    const int btile = grp * 8 + xcd;  // 0..255
    const int b0 = btile * BT;

    const int lane = t & 63;
    const int wv = t >> 6;            // 0..7: wave's M-tile (16 oc rows)
    const int lc = lane & 15;
    const int quad = lane >> 4;
    const int oc_base = wv * 16;

    // ---- staging loads: thread t owns rows (bl = bl0 + 4s, i = i_st), s=0..3.
    // Row = in[b0+bl, i, k, 0..8], 9 contiguous floats: 2x dwordx4 + 1 dword.
    // All 12 loads issued up front -> deep MLP; addresses are base + const.
    const int i_st = t & 127;
    const int bl0 = t >> 7;
    const float* rp = in + (size_t)(b0 + bl0) * (CINC * NK * NX)
                        + i_st * (NK * NX) + k * NX;
    F4 va[4], vb[4];
    float vc[4];
    #pragma unroll
    for (int s = 0; s < 4; ++s) {
        const float* p = rp + s * (4 * CINC * NK * NX);   // bl += 4 per step
        va[s] = *(const F4*)p;
        vb[s] = *(const F4*)(p + 4);
        vc[s] = p[8];
    }

    // ---- A-fragments direct from global (L2-hit; same data for all btiles),
    // issued while the staging loads are in flight.
    const float* wk = w + k * (COUTC * CINC);
    short8 afr[4];
    #pragma unroll
    for (int s = 0; s < 4; ++s) {
        const float* wp = wk + (oc_base + lc) * CINC + s * 32 + quad * 8;
        float4 w0 = *(const float4*)wp;
        float4 w1 = *(const float4*)(wp + 4);
        short8 a;
        a[0] = f2bf(w0.x); a[1] = f2bf(w0.y); a[2] = f2bf(w0.z); a[3] = f2bf(w0.w);
        a[4] = f2bf(w1.x); a[5] = f2bf(w1.y); a[6] = f2bf(w1.z); a[7] = f2bf(w1.w);
        afr[s] = a;
    }

    // ---- bias for this lane's 4 oc rows (row = quad*4 + reg)
    const float* bk = bias + k * COUTC;
    float bsv[4];
    #pragma unroll
    for (int r = 0; r < 4; ++r) bsv[r] = bk[oc_base + quad * 4 + r];

    // ---- convert + LDS write: col = (bl0+4s)*9 + x -> offset (36s+x)*LDK + i.
    // One base VGPR, 36 ds_write_b16 with immediate offsets (max 31552 < 64K).
    // Wave lanes carry consecutive i -> bank = (i>>1)+c: exactly 2-way (free).
    short* lb = &Il[(bl0 * NX) * LDK + i_st];
    #pragma unroll
    for (int s = 0; s < 4; ++s) {
        lb[(s * 36 + 0) * LDK] = f2bf(va[s].x);
        lb[(s * 36 + 1) * LDK] = f2bf(va[s].y);
        lb[(s * 36 + 2) * LDK] = f2bf(va[s].z);
        lb[(s * 36 + 3) * LDK] = f2bf(va[s].w);
        lb[(s * 36 + 4) * LDK] = f2bf(vb[s].x);
        lb[(s * 36 + 5) * LDK] = f2bf(vb[s].y);
        lb[(s * 36 + 6) * LDK] = f2bf(vb[s].z);
        lb[(s * 36 + 7) * LDK] = f2bf(vb[s].w);
        lb[(s * 36 + 8) * LDK] = f2bf(vc[s]);
    }

    __syncthreads();

    floatx4 acc[9];
    #pragma unroll
    for (int n = 0; n < 9; ++n) acc[n] = (floatx4){0.f, 0.f, 0.f, 0.f};

    // B-frag: B[kk][n=lane&15] read as Il[n][kk..kk+7]
    #pragma unroll
    for (int s = 0; s < 4; ++s) {
        int kof = s * 32 + quad * 8;
        #pragma unroll
        for (int n = 0; n < 9; ++n) {
            short8 bfr = *(const short8*)&Il[(n * 16 + lc) * LDK + kof];
            acc[n] = __builtin_amdgcn_mfma_f32_16x16x32_bf16(afr[s], bfr, acc[n], 0, 0, 0);
        }
    }

    // ---- store: out[b, k, oc, x]; C/D: col(lane&15)=nx, row(quad*4+r)=oc
    #pragma unroll
    for (int n = 0; n < 9; ++n) {
        int nx = n * 16 + lc;
        int bl = nx / 9;
        int x = nx - bl * 9;
        float* op = out + (size_t)(b0 + bl) * (NK * COUTC * NX) + k * (COUTC * NX)
                        + (oc_base + quad * 4) * NX + x;
        #pragma unroll
        for (int r = 0; r < 4; ++r)
            op[r * NX] = acc[n][r] + bsv[r];
    }
}

extern "C" void kernel_launch(void* const* d_in, const int* in_sizes, int n_in,
                              void* d_out, int out_size, void* d_ws, size_t ws_size,
                              hipStream_t stream) {
    const float* in  = (const float*)d_in[0];
    const float* w   = (const float*)d_in[1];
    const float* bs  = (const float*)d_in[2];
    float* out = (float*)d_out;
    dim3 grid((NB / BT) * NK);   // 2304 blocks, XCD-swizzled in-kernel
    dim3 block(512);
    GatherVertical_40656160424516_kernel<<<grid, block, 0, stream>>>(in, w, bs, out);
}

// Round 2
// 341.893 us; speedup vs baseline: 1.0560x; 1.0560x over previous
//
#include <hip/hip_runtime.h>
#include <hip/hip_bf16.h>

// out[b,k,oc,x] = sum_i W[k,oc,i] * in[b,i,k,x] + bias[k,oc]
// B=4096, Cin=Cout=128, K(offsets)=9, X=9.
// Memory-bound: 340 MB min traffic ~54us @6.3TB/s. bf16 MFMA compute ~4.6us.
// R1: XCD-aware swizzle (k-siblings of a btile share one XCD's L2); W direct from global.
// R2: (exonerated the load path) batched wide loads + affine staging: no effect ->
//     staging/MLP is NOT the binder. Reverted to R1's transaction-floor gather.
// R3: store-path fix. Old epilogue = 36 scalar dword stores/wave, each scattering
//     ~12 partial 36B line-fragments (432 line-touches/wave vs 144 floor), and on
//     the block critical path. New: after MFMA, reuse dead Il LDS as float buffer;
//     2 passes x 8 b-rows: scatter acc+bias into Ol[bl][oc][x] (2-way alias, free),
//     barrier, each wave bulk-copies one contiguous 4608B row with 4x dwordx4 +
//     1x dwordx2 (16 full lines/instr, store instrs 36 -> 10).

#define NB   4096
#define CINC 128
#define COUTC 128
#define NK   9
#define NX   9
#define BT   16               // b's per workgroup
#define NCOL (BT * NX)        // 144 columns per workgroup
#define LDK  136              // padded row length (shorts): 16B-aligned rows

typedef __attribute__((ext_vector_type(8))) short short8;
typedef __attribute__((ext_vector_type(4))) float floatx4;
typedef __attribute__((ext_vector_type(2))) float floatx2;

__device__ __forceinline__ short f2bf(float f) {
    union { float f; unsigned u; } v; v.f = f;
    unsigned r = v.u + 0x7fff + ((v.u >> 16) & 1);  // RNE; inputs are finite normals
    return (short)(r >> 16);
}

__global__ __launch_bounds__(512, 6) void GatherVertical_40656160424516_kernel(
    const float* __restrict__ in, const float* __restrict__ w,
    const float* __restrict__ bias, float* __restrict__ out)
{
    // Aliased LDS: bf16 input tile Il[144][136] during MFMA phase (39168 B),
    // then float relayout buffer Ol[8][128][9] (36864 B) during the epilogue.
    __shared__ __align__(16) char smem[NCOL * LDK * 2];
    short* Il = (short*)smem;

    const int t = threadIdx.x;

    // ---- XCD swizzle: siblings (same btile, k=0..8) land on the same XCD,
    // adjacent in that XCD's dispatch stream.
    const int j = blockIdx.x;
    const int xcd = j & 7;
    const int slot = j >> 3;          // 0..287 per XCD
    const int grp = slot / 9;         // 0..31
    const int k = slot - grp * 9;     // 0..8
    const int btile = grp * 8 + xcd;  // 0..255
    const int b0 = btile * BT;

    const int lane = t & 63;
    const int wv = t >> 6;            // 0..7: wave's M-tile (16 oc rows)
    const int lc = lane & 15;
    const int quad = lane >> 4;
    const int oc_base = wv * 16;

    // ---- A-fragments direct from global (L2-hit; same data for all 256 btiles).
    // A[m=lane&15][kk=quad*8+j], four K-steps of 32.
    const float* wk = w + k * (COUTC * CINC);
    short8 afr[4];
    #pragma unroll
    for (int s = 0; s < 4; ++s) {
        const float* wp = wk + (oc_base + lc) * CINC + s * 32 + quad * 8;
        float4 w0 = *(const float4*)wp;
        float4 w1 = *(const float4*)(wp + 4);
        short8 a;
        a[0] = f2bf(w0.x); a[1] = f2bf(w0.y); a[2] = f2bf(w0.z); a[3] = f2bf(w0.w);
        a[4] = f2bf(w1.x); a[5] = f2bf(w1.y); a[6] = f2bf(w1.z); a[7] = f2bf(w1.w);
        afr[s] = a;
    }

    // ---- bias for this lane's 4 oc rows (row = quad*4 + reg)
    const float* bk = bias + k * COUTC;
    float bsv[4];
    #pragma unroll
    for (int r = 0; r < 4; ++r) bsv[r] = bk[oc_base + quad * 4 + r];

    // ---- stage input tile: in[b0+bl, i, k, x] -> Il[bl*9+x][i]
    // x fastest across threads: each wave instruction covers ~7 consecutive
    // (i) rows' 36B runs -> ~11 lines/instr = transaction floor for this gather.
    const float* inb = in + (size_t)b0 * (CINC * NK * NX) + k * NX;
    #pragma unroll
    for (int it = 0; it < 36; ++it) {
        int f = it * 512 + t;                    // 0..18431
        int bl = f / (CINC * NX);                // /1152 (magic mul)
        int rem = f - bl * (CINC * NX);
        int i = rem / NX;
        int x = rem - i * NX;
        float v = inb[bl * (CINC * NK * NX) + i * (NK * NX) + x];
        Il[(bl * NX + x) * LDK + i] = f2bf(v);
    }

    __syncthreads();

    floatx4 acc[9];
    #pragma unroll
    for (int n = 0; n < 9; ++n) acc[n] = (floatx4){0.f, 0.f, 0.f, 0.f};

    // B-frag: B[kk][n=lane&15] read as Il[n][kk..kk+7]
    #pragma unroll
    for (int s = 0; s < 4; ++s) {
        int kof = s * 32 + quad * 8;
        #pragma unroll
        for (int n = 0; n < 9; ++n) {
            short8 bfr = *(const short8*)&Il[(n * 16 + lc) * LDK + kof];
            acc[n] = __builtin_amdgcn_mfma_f32_16x16x32_bf16(afr[s], bfr, acc[n], 0, 0, 0);
        }
    }

    // ---- epilogue: LDS relayout -> fully coalesced stores.
    // C/D frag: col(lane&15)=nx=n*16+lc -> (bl=nx/9, x=nx%9); row(quad*4+r)=oc.
    // Pass p covers bl in [8p, 8p+8): scatter into Ol[bl&7][oc][x], barrier,
    // then wave wv streams row bl=8p+wv (1152 floats contiguous) to global.
    for (int p = 0; p < 2; ++p) {
        __syncthreads();   // p=0: Il reads done; p=1: pass-0 Ol reads done
        float* Ol = (float*)smem;
        #pragma unroll
        for (int n = 0; n < 9; ++n) {
            int nx = n * 16 + lc;
            int bl = nx / 9;
            if ((bl >> 3) == p) {
                int x = nx - bl * 9;
                int base = ((bl & 7) * COUTC + oc_base + quad * 4) * NX + x;
                #pragma unroll
                for (int r = 0; r < 4; ++r)
                    Ol[base + r * NX] = acc[n][r] + bsv[r];
            }
        }
        __syncthreads();
        const float* src = Ol + wv * (COUTC * NX);
        float* dst = out + (size_t)(b0 + p * 8 + wv) * (NK * COUTC * NX)
                         + k * (COUTC * NX);
        #pragma unroll
        for (int s = 0; s < 4; ++s) {
            floatx4 v = *(const floatx4*)(src + s * 256 + lane * 4);
            *(floatx4*)(dst + s * 256 + lane * 4) = v;
        }
        floatx2 v2 = *(const floatx2*)(src + 1024 + lane * 2);
        *(floatx2*)(dst + 1024 + lane * 2) = v2;
    }
}

extern "C" void kernel_launch(void* const* d_in, const int* in_sizes, int n_in,
                              void* d_out, int out_size, void* d_ws, size_t ws_size,
                              hipStream_t stream) {
    const float* in  = (const float*)d_in[0];
    const float* w   = (const float*)d_in[1];
    const float* bs  = (const float*)d_in[2];
    float* out = (float*)d_out;
    dim3 grid((NB / BT) * NK);   // 2304 blocks, XCD-swizzled in-kernel
    dim3 block(512);
    GatherVertical_40656160424516_kernel<<<grid, block, 0, stream>>>(in, w, bs, out);
}